// Round 5
// baseline (1399.883 us; speedup 1.0000x reference)
//
#include <hip/hip_runtime.h>
#include <math.h>

#define RES   1024
#define FEATC 12
#define CBN   32
#define H_IMG 1080
#define W_IMG 1920
#define NPIX  (H_IMG * W_IMG)
#define SEG   2048          // pixels per block
#define PPT   (SEG / 256)   // compaction rounds per block

// Per-pixel pipeline. Math identical to round-2's passing kernel on the
// continuous path (elementwise-rounded sample path, k-outer MLP with j-ascending
// accumulation); argmin is the fp64 dot-form validated in round 3.
// Weights/biases read DIRECTLY from global with wave-uniform constant indices
// so the compiler scalarizes them to s_load (scalar pipe, K$) instead of LDS.
__device__ __forceinline__ void shade_pixel(
    int i,
    const float* __restrict__ rays_d,
    const float* __restrict__ cube,
    const float* __restrict__ W1, const float* __restrict__ b1,
    const float* __restrict__ W2, const float* __restrict__ b2,
    const float* __restrict__ W3, const float* __restrict__ b3,
    const float*  sCB,     // fp32 codebook in LDS (divergent access by 'best')
    const double* sCBd,    // fp64 codebook in LDS (uniform broadcast reads)
    const double* sCN,     // fp64 ||c_j||^2 in LDS
    float* __restrict__ out)
{
    const float x = rays_d[3 * i + 0];
    const float y = rays_d[3 * i + 1];
    const float z = rays_d[3 * i + 2];

    const float ax = fabsf(x), ay = fabsf(y), az = fabsf(z);
    const bool is_x = (ax >= ay) && (ax >= az);
    const bool is_y = (!is_x) && (ay >= az);

    int face; float ma, u, v;
    if (is_x) {
        face = (x >= 0.0f) ? 0 : 1;
        ma = ax; u = (x >= 0.0f) ? -z : z; v = -y;
    } else if (is_y) {
        face = (y >= 0.0f) ? 2 : 3;
        ma = ay; u = x; v = (y >= 0.0f) ? z : -z;
    } else {
        face = (z >= 0.0f) ? 4 : 5;
        ma = az; u = (z >= 0.0f) ? x : -x; v = -y;
    }

    const float denom = __fadd_rn(ma, 1e-9f);
    const float s = __fsub_rn(__fmul_rn(__fmul_rn(__fadd_rn(__fdiv_rn(u, denom), 1.0f), 0.5f), (float)RES), 0.5f);
    const float t = __fsub_rn(__fmul_rn(__fmul_rn(__fadd_rn(__fdiv_rn(v, denom), 1.0f), 0.5f), (float)RES), 0.5f);

    const float x0f = floorf(s);
    const float y0f = floorf(t);
    const float fx = __fsub_rn(s, x0f);
    const float fy = __fsub_rn(t, y0f);

    int x0i = (int)x0f; x0i = min(max(x0i, 0), RES - 1);
    int x1i = min(x0i + 1, RES - 1);
    int y0i = (int)y0f; y0i = min(max(y0i, 0), RES - 1);
    int y1i = min(y0i + 1, RES - 1);

    const size_t fbase = (size_t)face * RES * RES;
    const float4* p00 = (const float4*)(cube + (fbase + (size_t)y0i * RES + x0i) * FEATC);
    const float4* p01 = (const float4*)(cube + (fbase + (size_t)y0i * RES + x1i) * FEATC);
    const float4* p10 = (const float4*)(cube + (fbase + (size_t)y1i * RES + x0i) * FEATC);
    const float4* p11 = (const float4*)(cube + (fbase + (size_t)y1i * RES + x1i) * FEATC);

    float c00[FEATC], c01[FEATC], c10[FEATC], c11[FEATC];
    #pragma unroll
    for (int q4 = 0; q4 < 3; ++q4) {
        float4 a = p00[q4]; c00[4*q4+0]=a.x; c00[4*q4+1]=a.y; c00[4*q4+2]=a.z; c00[4*q4+3]=a.w;
        float4 b = p01[q4]; c01[4*q4+0]=b.x; c01[4*q4+1]=b.y; c01[4*q4+2]=b.z; c01[4*q4+3]=b.w;
        float4 c = p10[q4]; c10[4*q4+0]=c.x; c10[4*q4+1]=c.y; c10[4*q4+2]=c.z; c10[4*q4+3]=c.w;
        float4 dd= p11[q4]; c11[4*q4+0]=dd.x;c11[4*q4+1]=dd.y;c11[4*q4+2]=dd.z;c11[4*q4+3]=dd.w;
    }

    const float omfx = __fsub_rn(1.0f, fx);
    const float omfy = __fsub_rn(1.0f, fy);
    float feat[FEATC];
    double featd[FEATC];
    #pragma unroll
    for (int k = 0; k < FEATC; ++k) {
        const float top = __fadd_rn(__fmul_rn(c00[k], omfx), __fmul_rn(c01[k], fx));
        const float bot = __fadd_rn(__fmul_rn(c10[k], omfx), __fmul_rn(c11[k], fx));
        feat[k] = __fadd_rn(__fmul_rn(top, omfy), __fmul_rn(bot, fy));
        featd[k] = (double)feat[k];
    }

    // fp64 dot-form argmin (round-3-validated): argmin_j ||c_j||^2 - 2 f.c_j
    int best = 0;
    double bestd = 1e300;
    for (int j = 0; j < CBN; ++j) {
        double dot = 0.0;
        #pragma unroll
        for (int k = 0; k < FEATC; ++k)
            dot = fma(featd[k], sCBd[j * FEATC + k], dot);
        const double d2 = fma(-2.0, dot, sCN[j]);
        if (d2 < bestd) { bestd = d2; best = j; }
    }

    float hin[15];
    #pragma unroll
    for (int k = 0; k < FEATC; ++k)
        hin[k] = __fadd_rn(feat[k], __fsub_rn(sCB[best * FEATC + k], feat[k]));
    hin[12] = x; hin[13] = y; hin[14] = z;

    // MLP: k-outer (round-2 accumulation order), weights via uniform global
    // reads -> scalar loads on the K$ path, VALU does only v_fmac.
    float h1[32];
    #pragma unroll
    for (int k = 0; k < 32; ++k) {
        float a = b1[k];
        #pragma unroll
        for (int j = 0; j < 15; ++j) a += hin[j] * W1[j * 32 + k];
        h1[k] = fmaxf(a, 0.0f);
    }

    float h2[32];
    #pragma unroll
    for (int k = 0; k < 32; ++k) {
        float a = b2[k];
        #pragma unroll
        for (int j = 0; j < 32; ++j) a += h1[j] * W2[j * 32 + k];
        h2[k] = fmaxf(a, 0.0f);
    }

    #pragma unroll
    for (int c = 0; c < 3; ++c) {
        float a = b3[c];
        #pragma unroll
        for (int j = 0; j < 32; ++j) a += h2[j] * W3[j * 3 + c];
        float r = 1.0f / (1.0f + expf(-a));
        r = fminf(fmaxf(r, 0.0f), 1.0f);
        out[(size_t)c * NPIX + i] = r;
    }
}

__global__ __launch_bounds__(256, 4) void sky_fused(
    const float* __restrict__ rays_d,   // [NPIX,3]
    const int*   __restrict__ mask,     // [NPIX]
    const float* __restrict__ cube,     // [6,RES,RES,12]
    const float* __restrict__ cb,       // [32,12]
    const float* __restrict__ W1, const float* __restrict__ b1,
    const float* __restrict__ W2, const float* __restrict__ b2,
    const float* __restrict__ W3, const float* __restrict__ b3,
    float*       __restrict__ out)      // [3,NPIX]
{
    __shared__ float  sCB[CBN * FEATC];    // 1.5 KB
    __shared__ double sCBd[CBN * FEATC];   // 3 KB
    __shared__ double sCN[CBN];            // 256 B
    __shared__ int    sList[SEG];          // 8 KB
    __shared__ int    sWsum[4];

    for (int t = threadIdx.x; t < CBN * FEATC; t += blockDim.x) {
        const float c = cb[t];
        sCB[t] = c;
        sCBd[t] = (double)c;
    }
    if (threadIdx.x < CBN) {
        double sum = 0.0;
        #pragma unroll
        for (int k = 0; k < FEATC; ++k) {
            const double c = (double)cb[threadIdx.x * FEATC + k];
            sum = fma(c, c, sum);
        }
        sCN[threadIdx.x] = sum;
    }
    __syncthreads();

    const int tid  = threadIdx.x;
    const int lane = tid & 63;
    const int wid  = tid >> 6;
    const int seg0 = blockIdx.x * SEG;

    // ---- phase 1: block compaction (ascending), zero inactive outputs ----
    int nAct = 0;
    #pragma unroll
    for (int r = 0; r < PPT; ++r) {
        const int i = seg0 + r * 256 + tid;   // coalesced
        bool act = false;
        if (i < NPIX) {
            act = (mask[i] != 0);
            if (!act) {
                out[0 * NPIX + i] = 0.0f;
                out[1 * NPIX + i] = 0.0f;
                out[2 * NPIX + i] = 0.0f;
            }
        }
        const unsigned long long bal = __ballot(act);
        const int rank = __popcll(bal & ((1ull << lane) - 1ull));
        if (lane == 0) sWsum[wid] = (int)__popcll(bal);
        __syncthreads();
        int woff = 0;
        #pragma unroll
        for (int w = 0; w < 4; ++w) woff += (w < wid) ? sWsum[w] : 0;
        const int wtot = sWsum[0] + sWsum[1] + sWsum[2] + sWsum[3];
        if (act) sList[nAct + woff + rank] = i;
        nAct += wtot;
        __syncthreads();
    }

    // ---- phase 2: shade packed actives, one iteration live at a time ----
    #pragma unroll 1
    for (int t = tid; t < nAct; t += 256) {
        shade_pixel(sList[t], rays_d, cube,
                    W1, b1, W2, b2, W3, b3,
                    sCB, sCBd, sCN, out);
    }
}

extern "C" void kernel_launch(void* const* d_in, const int* in_sizes, int n_in,
                              void* d_out, int out_size, void* d_ws, size_t ws_size,
                              hipStream_t stream) {
    const float* rays_d = (const float*)d_in[0];
    const int*   mask   = (const int*)d_in[1];
    const float* cube   = (const float*)d_in[2];
    const float* cb     = (const float*)d_in[3];
    const float* W1     = (const float*)d_in[4];
    const float* b1     = (const float*)d_in[5];
    const float* W2     = (const float*)d_in[6];
    const float* b2     = (const float*)d_in[7];
    const float* W3     = (const float*)d_in[8];
    const float* b3     = (const float*)d_in[9];
    float* out = (float*)d_out;

    const int grid = (NPIX + SEG - 1) / SEG;  // 1013
    sky_fused<<<grid, 256, 0, stream>>>(rays_d, mask, cube, cb,
                                        W1, b1, W2, b2, W3, b3, out);
}